// Round 8
// baseline (274.142 us; speedup 1.0000x reference)
//
#include <hip/hip_runtime.h>

typedef unsigned short u16;
typedef __attribute__((ext_vector_type(8))) short bf16x8;
typedef __attribute__((ext_vector_type(4))) short bf16x4;
typedef __attribute__((ext_vector_type(4))) float f32x4;

// ---------- helpers ----------
__device__ __forceinline__ u16 f2bf(float f) {
  unsigned u = __float_as_uint(f);
  u += 0x7FFFu + ((u >> 16) & 1u);   // RNE
  return (u16)(u >> 16);
}
__device__ __forceinline__ unsigned pack2(float a, float b) {
  return (unsigned)f2bf(a) | ((unsigned)f2bf(b) << 16);
}
#if __has_builtin(__builtin_amdgcn_cvt_pk_bf16_f32)
typedef __attribute__((ext_vector_type(2))) __bf16 bf16v2;
__device__ __forceinline__ unsigned cvt_pk(float a, float b) {
  bf16v2 v = __builtin_amdgcn_cvt_pk_bf16_f32(a, b);
  return __builtin_bit_cast(unsigned, v);
}
#else
__device__ __forceinline__ unsigned cvt_pk(float a, float b) { return pack2(a, b); }
#endif
__device__ __forceinline__ uint4 pack8(float4 a, float4 b) {
  uint4 r;
  r.x = pack2(a.x, a.y); r.y = pack2(a.z, a.w);
  r.z = pack2(b.x, b.y); r.w = pack2(b.z, b.w);
  return r;
}
__device__ __forceinline__ void gload16(const void* g, void* l) {
  __builtin_amdgcn_global_load_lds(
      (const __attribute__((address_space(1))) void*)g,
      (__attribute__((address_space(3))) void*)l, 16, 0, 0);
}
// 16x16x16 bf16 MFMA (A-frag layout == 16x16 C/D layout -> P stays in regs)
__device__ __forceinline__ f32x4 mfma16(bf16x4 a, bf16x4 b, f32x4 c) {
#if __has_builtin(__builtin_amdgcn_mfma_f32_16x16x16bf16_1k)
  return __builtin_amdgcn_mfma_f32_16x16x16bf16_1k(a, b, c, 0, 0, 0);
#elif __has_builtin(__builtin_amdgcn_mfma_f32_16x16x16_bf16)
  return __builtin_amdgcn_mfma_f32_16x16x16_bf16(a, b, c, 0, 0, 0);
#else
  asm volatile("v_mfma_f32_16x16x16_bf16 %0, %1, %2, %0\n\ts_nop 2"
               : "+v"(c) : "v"(a), "v"(b));
  return c;
#endif
}

// ---------- fused prep: cvt x -> bf16 | transpose Wq/Wk/Wv | cvt Wp ----------
__global__ __launch_bounds__(256) void prep(
    const float* __restrict__ x, u16* __restrict__ xbf,
    const float* __restrict__ Wq, const float* __restrict__ Wk,
    const float* __restrict__ Wv, u16* __restrict__ wt,
    const float* __restrict__ Wp, u16* __restrict__ wpbf) {
  const int tid = threadIdx.x;
  const int b = blockIdx.x;
  __shared__ __align__(16) u16 tile[64 * 72];
  if (b < 4096) {
    const size_t i = (size_t)b * 256 + tid;
    const float4* p = (const float4*)(x + i * 8);
    *(uint4*)(xbf + i * 8) = pack8(p[0], p[1]);
  } else if (b < 4864) {
    const int idx = b - 4096;
    const int w = idx >> 8;                 // which weight
    const int mat = (idx >> 4) & 15;        // head
    const int r0 = (idx & 15) * 64;         // row block
    const float* src = (w == 0 ? Wq : (w == 1 ? Wk : Wv)) + (size_t)mat * 1024 * 64;
    u16* dst = wt + (size_t)w * 1024 * 1024 + (size_t)mat * 1024 * 64;
#pragma unroll
    for (int i = 0; i < 2; ++i) {
      const int c = tid + i * 256;
      const int r = c >> 3, off = (c & 7) * 8;
      const float* p = src + (size_t)(r0 + r) * 64 + off;
      *(uint4*)(&tile[r * 72 + off]) = pack8(*(const float4*)p, *(const float4*)(p + 4));
    }
    __syncthreads();
#pragma unroll
    for (int i = 0; i < 2; ++i) {
      const int c = tid + i * 256;
      const int d = c >> 3, roff = (c & 7) * 8;
      bf16x8 v;
#pragma unroll
      for (int j = 0; j < 8; ++j) v[j] = (short)tile[(roff + j) * 72 + d];
      *(bf16x8*)(dst + (size_t)d * 1024 + r0 + roff) = v;
    }
  } else {
    const size_t i = (size_t)(b - 4864) * 256 + tid;
    const float4* p = (const float4*)(Wp + i * 8);
    *(uint4*)(wpbf + i * 8) = pack8(p[0], p[1]);
  }
}

// ---------- gemm_bt (bf16 operands, global_load_lds staging, m97 pattern) ----------
// MODE 0: o0=Q (PRE-SCALED by 0.125*log2e), o1=K as [B,H,T,D]; o2=V TRANSPOSED [B,H,D,T].
// MODE 1: fout[M,1024] FP32 + bias bp.
template <int MODE>
__global__ __launch_bounds__(256) void gemm_bt(
    const u16* __restrict__ A, const u16* __restrict__ BT,
    u16* __restrict__ o0, u16* __restrict__ o1, u16* __restrict__ o2,
    float* __restrict__ fout, const float* __restrict__ bp) {
  __shared__ __align__(16) u16 As[128 * 32];
  __shared__ __align__(16) u16 Bs[128 * 32];
  const int tid = threadIdx.x;
  const int lane = tid & 63, wv = tid >> 6;
  const int g = lane >> 4, ln = lane & 15;
  const int wm = wv >> 1, wn = wv & 1;
  const int m0 = blockIdx.x * 128, n0 = blockIdx.y * 128;

  const f32x4 fz = {0.f, 0.f, 0.f, 0.f};
  f32x4 acc[4][4];
#pragma unroll
  for (int i = 0; i < 4; ++i)
#pragma unroll
    for (int j = 0; j < 4; ++j) acc[i][j] = fz;

  for (int k0 = 0; k0 < 1024; k0 += 32) {
    __syncthreads();
#pragma unroll
    for (int i = 0; i < 2; ++i) {
      const int c = tid + i * 256;
      const int r = c >> 2, off = (c & 3) * 8;
      gload16(A + (size_t)(m0 + r) * 1024 + k0 + off, &As[c * 8]);
      gload16(BT + (size_t)(n0 + r) * 1024 + k0 + off, &Bs[c * 8]);
    }
    __syncthreads();
    bf16x8 af[4], bfr[4];
#pragma unroll
    for (int rt = 0; rt < 4; ++rt)
      af[rt] = *(const bf16x8*)(&As[(wm * 64 + rt * 16 + ln) * 32 + g * 8]);
#pragma unroll
    for (int ct = 0; ct < 4; ++ct)
      bfr[ct] = *(const bf16x8*)(&Bs[(wn * 64 + ct * 16 + ln) * 32 + g * 8]);
#pragma unroll
    for (int rt = 0; rt < 4; ++rt)
#pragma unroll
      for (int ct = 0; ct < 4; ++ct)
        acc[rt][ct] = __builtin_amdgcn_mfma_f32_16x16x32_bf16(af[rt], bfr[ct],
                                                              acc[rt][ct], 0, 0, 0);
  }

  if (MODE == 0) {
    const int which = n0 >> 10;
    const int nl0 = (n0 & 1023) + wn * 64;
    const float qs = (which == 0) ? 0.1803368801f : 1.0f;  // 0.125*log2(e) for Q
    if (which < 2) {
      u16* outp = which == 0 ? o0 : o1;
#pragma unroll
      for (int rt = 0; rt < 4; ++rt)
#pragma unroll
        for (int ct = 0; ct < 4; ++ct) {
          const int nl = nl0 + ct * 16 + ln;
          const int h = nl >> 6, d = nl & 63;
#pragma unroll
          for (int r = 0; r < 4; ++r) {
            const int m = m0 + wm * 64 + rt * 16 + 4 * g + r;
            const int b = m >> 11, t = m & 2047;
            outp[(((size_t)(b * 16 + h) * 2048 + t) << 6) + d] =
                f2bf(acc[rt][ct][r] * qs);
          }
        }
    } else {
#pragma unroll
      for (int rt = 0; rt < 4; ++rt) {
        const int tb = m0 + wm * 64 + rt * 16 + 4 * g;  // multiple of 4
        const int b = tb >> 11, t = tb & 2047;
#pragma unroll
        for (int ct = 0; ct < 4; ++ct) {
          const int nl = nl0 + ct * 16 + ln;
          const int h = nl >> 6, d = nl & 63;
          u16* dst = o2 + ((size_t)((b * 16 + h) * 64 + d) << 11) + t;
#pragma unroll
          for (int r = 0; r < 4; ++r) dst[r] = f2bf(acc[rt][ct][r]);
        }
      }
    }
  } else {
#pragma unroll
    for (int ct = 0; ct < 4; ++ct) {
      const int n = n0 + wn * 64 + ct * 16 + ln;
      const float bias = bp[n];
#pragma unroll
      for (int rt = 0; rt < 4; ++rt)
#pragma unroll
        for (int r = 0; r < 4; ++r) {
          const int m = m0 + wm * 64 + rt * 16 + 4 * g + r;
          fout[(size_t)m * 1024 + n] = acc[rt][ct][r] + bias;
        }
    }
  }
}

// ---------- flash attention v4, causal, uniform-work pairing ----------
// 64-row q-segments (32 total). Block (bh, j) runs segment j then segment 31-j
// sequentially -> every block stages exactly 33 k-tiles (uniform drain, 4 blk/CU).
// S^T = K Q^T (C/D layout == 16x16x16 A-frag layout -> P stays in registers).
// Unnormalized softmax (Q pre-scaled by 0.125*log2e); l via ones-fragment MFMA.
// grid (bh=64, j=16): all blocks of a head land on XCD bh%8 (K/V L2 locality).
__global__ __launch_bounds__(256) void attn_kernel(
    const u16* __restrict__ Q, const u16* __restrict__ K,
    const u16* __restrict__ VT, u16* __restrict__ AO) {
  const int tid = threadIdx.x;
  const int wv = tid >> 6, lane = tid & 63, g = lane >> 4, ln = lane & 15;
  const int bh = blockIdx.x;
  const int jb = blockIdx.y;
  const u16* Qb = Q + (size_t)bh * (2048 * 64);
  const u16* Kb = K + (size_t)bh * (2048 * 64);
  const u16* Vb = VT + (size_t)bh * (64 * 2048);

  __shared__ __align__(16) u16 Ks[64 * 72];
  __shared__ __align__(16) u16 Vs[64 * 72];

  const int sr0 = tid >> 3, so0 = (tid & 7) * 8;
  const int sr1 = sr0 + 32;  // (tid+256)>>3 ; offset unchanged

  // prefetch phase-0 tile 0 (s = 0)
  uint4 kpf0 = *(const uint4*)(Kb + (size_t)sr0 * 64 + so0);
  uint4 kpf1 = *(const uint4*)(Kb + (size_t)sr1 * 64 + so0);
  uint4 vpf0 = *(const uint4*)(Vb + (size_t)sr0 * 2048 + so0);
  uint4 vpf1 = *(const uint4*)(Vb + (size_t)sr1 * 2048 + so0);

  const int b = bh >> 4, h = bh & 15;
  const short ob = 0x3F80;
  const bf16x4 ones = {ob, ob, ob, ob};
  const f32x4 fz = {0.f, 0.f, 0.f, 0.f};

#pragma unroll
  for (int ph = 0; ph < 2; ++ph) {
    const int qi = (ph == 0) ? jb : 31 - jb;
    const int q0 = qi * 64;
    const int nt = qi + 1;
    const int qrow = q0 + wv * 16 + ln;     // this lane's q index (S^T column)
    const bf16x8 qa0 = *(const bf16x8*)(Qb + (size_t)qrow * 64 + g * 8);
    const bf16x8 qa1 = *(const bf16x8*)(Qb + (size_t)qrow * 64 + 32 + g * 8);

    f32x4 oacc[4];
    f32x4 lacc = fz;
#pragma unroll
    for (int dt = 0; dt < 4; ++dt) oacc[dt] = fz;

    for (int kt = 0; kt < nt; ++kt) {
      __syncthreads();
      *(uint4*)(&Ks[sr0 * 72 + so0]) = kpf0;
      *(uint4*)(&Ks[sr1 * 72 + so0]) = kpf1;
      *(uint4*)(&Vs[sr0 * 72 + so0]) = vpf0;
      *(uint4*)(&Vs[sr1 * 72 + so0]) = vpf1;
      __syncthreads();
      // prefetch next tile (next kt, or tile 0 of phase B)
      if ((kt + 1 < nt) || (ph == 0)) {
        const int sn = (kt + 1 < nt) ? (kt + 1) * 64 : 0;
        kpf0 = *(const uint4*)(Kb + (size_t)(sn + sr0) * 64 + so0);
        kpf1 = *(const uint4*)(Kb + (size_t)(sn + sr1) * 64 + so0);
        vpf0 = *(const uint4*)(Vb + (size_t)sr0 * 2048 + sn + so0);
        vpf1 = *(const uint4*)(Vb + (size_t)sr1 * 2048 + sn + so0);
      }
      // S^T = K Q^T  (lane holds s = st*16+4g+r, q = qrow)
      f32x4 sfT[4];
#pragma unroll
      for (int st = 0; st < 4; ++st) sfT[st] = fz;
#pragma unroll
      for (int st = 0; st < 4; ++st) {
        const bf16x8 kb0 = *(const bf16x8*)(&Ks[(st * 16 + ln) * 72 + g * 8]);
        const bf16x8 kb1 = *(const bf16x8*)(&Ks[(st * 16 + ln) * 72 + 32 + g * 8]);
        sfT[st] = __builtin_amdgcn_mfma_f32_16x16x32_bf16(kb0, qa0, sfT[st], 0, 0, 0);
        sfT[st] = __builtin_amdgcn_mfma_f32_16x16x32_bf16(kb1, qa1, sfT[st], 0, 0, 0);
      }
      // exp (Q pre-scaled); causal mask only on diagonal tile; pack pairs
      const bool diag = (kt == nt - 1);
      bf16x4 pa[4];
#pragma unroll
      for (int st = 0; st < 4; ++st) {
        float e[4];
#pragma unroll
        for (int r = 0; r < 4; ++r) e[r] = __builtin_amdgcn_exp2f(sfT[st][r]);
        if (diag) {
#pragma unroll
          for (int r = 0; r < 4; ++r)
            if (st * 16 + 4 * g + r > wv * 16 + ln) e[r] = 0.f;
        }
        uint2 packed = {cvt_pk(e[0], e[1]), cvt_pk(e[2], e[3])};
        pa[st] = __builtin_bit_cast(bf16x4, packed);
      }
      // O += P V ; l += P . ones
#pragma unroll
      for (int st = 0; st < 4; ++st) {
#pragma unroll
        for (int dt = 0; dt < 4; ++dt) {
          const bf16x4 vb =
              *(const bf16x4*)(&Vs[(dt * 16 + ln) * 72 + st * 16 + 4 * g]);
          oacc[dt] = mfma16(pa[st], vb, oacc[dt]);
        }
        lacc = mfma16(pa[st], ones, lacc);
      }
    }
    // epilogue for this segment (oacc rows: q = q0 + wv*16 + 4g + r, col d)
    float linv[4];
#pragma unroll
    for (int r = 0; r < 4; ++r) linv[r] = 1.f / lacc[r];
#pragma unroll
    for (int dt = 0; dt < 4; ++dt)
#pragma unroll
      for (int r = 0; r < 4; ++r) {
        const int qg = q0 + wv * 16 + 4 * g + r;
        AO[(size_t)(b * 2048 + qg) * 1024 + h * 64 + dt * 16 + ln] =
            f2bf(oacc[dt][r] * linv[r]);
      }
  }
}

// ---------- launch ----------
// Inputs FP32, output FP32; internal bf16. ws (72 MB, proven r7):
//   [0,16M): xbf (phase 1) then AO (phase 2)
//   [16,22M): wt    [22,24M): wpbf
//   Q [24,40M)   K [40,56M)   VT [56,72M)
extern "C" void kernel_launch(void* const* d_in, const int* in_sizes, int n_in,
                              void* d_out, int out_size, void* d_ws, size_t ws_size,
                              hipStream_t stream) {
  const float* x  = (const float*)d_in[0];
  const float* Wq = (const float*)d_in[1];
  const float* Wk = (const float*)d_in[2];
  const float* Wv = (const float*)d_in[3];
  const float* Wp = (const float*)d_in[4];
  const float* bp = (const float*)d_in[5];
  float* out = (float*)d_out;

  char* ws = (char*)d_ws;
  const size_t MB = 1048576;
  u16* xbf  = (u16*)(ws);
  u16* aows = (u16*)(ws);
  u16* wt   = (u16*)(ws + 16 * MB);
  u16* wpbf = (u16*)(ws + 22 * MB);
  u16* qws  = (u16*)(ws + 24 * MB);
  u16* kws  = (u16*)(ws + 40 * MB);
  u16* vtws = (u16*)(ws + 56 * MB);

  // fused prep: x->bf16, Wq/Wk/Wv -> WT[3072][1024] bf16, Wp->bf16
  prep<<<dim3(5376), 256, 0, stream>>>(x, xbf, Wq, Wk, Wv, wt, Wp, wpbf);
  // QKV projection -> Q(prescaled),K [B,H,T,D]; V direct-transposed [B,H,D,T]
  gemm_bt<0><<<dim3(64, 24), 256, 0, stream>>>(xbf, wt, qws, kws, vtws,
                                               nullptr, nullptr);
  // causal flash attention -> AO [B,T,H*D] (overlays dead xbf)
  attn_kernel<<<dim3(64, 16), 256, 0, stream>>>(qws, kws, vtws, aows);
  // output projection: AO @ Wp^T + bp -> out FP32
  gemm_bt<1><<<dim3(64, 8), 256, 0, stream>>>(aows, wpbf, nullptr, nullptr,
                                              nullptr, out, bp);
}

// Round 9
// 268.162 us; speedup vs baseline: 1.0223x; 1.0223x over previous
//
#include <hip/hip_runtime.h>

typedef unsigned short u16;
typedef __attribute__((ext_vector_type(8))) short bf16x8;
typedef __attribute__((ext_vector_type(4))) short bf16x4;
typedef __attribute__((ext_vector_type(4))) float f32x4;

// ---------- helpers ----------
__device__ __forceinline__ u16 f2bf(float f) {
  unsigned u = __float_as_uint(f);
  u += 0x7FFFu + ((u >> 16) & 1u);   // RNE
  return (u16)(u >> 16);
}
__device__ __forceinline__ unsigned pack2(float a, float b) {
  return (unsigned)f2bf(a) | ((unsigned)f2bf(b) << 16);
}
#if __has_builtin(__builtin_amdgcn_cvt_pk_bf16_f32)
typedef __attribute__((ext_vector_type(2))) __bf16 bf16v2;
__device__ __forceinline__ unsigned cvt_pk(float a, float b) {
  bf16v2 v = __builtin_amdgcn_cvt_pk_bf16_f32(a, b);
  return __builtin_bit_cast(unsigned, v);
}
#else
__device__ __forceinline__ unsigned cvt_pk(float a, float b) { return pack2(a, b); }
#endif
__device__ __forceinline__ uint4 pack8(float4 a, float4 b) {
  uint4 r;
  r.x = pack2(a.x, a.y); r.y = pack2(a.z, a.w);
  r.z = pack2(b.x, b.y); r.w = pack2(b.z, b.w);
  return r;
}
__device__ __forceinline__ void gload16(const void* g, void* l) {
  __builtin_amdgcn_global_load_lds(
      (const __attribute__((address_space(1))) void*)g,
      (__attribute__((address_space(3))) void*)l, 16, 0, 0);
}
// 16x16x16 bf16 MFMA (A-frag layout == 16x16 C/D layout -> P stays in regs)
__device__ __forceinline__ f32x4 mfma16(bf16x4 a, bf16x4 b, f32x4 c) {
#if __has_builtin(__builtin_amdgcn_mfma_f32_16x16x16bf16_1k)
  return __builtin_amdgcn_mfma_f32_16x16x16bf16_1k(a, b, c, 0, 0, 0);
#elif __has_builtin(__builtin_amdgcn_mfma_f32_16x16x16_bf16)
  return __builtin_amdgcn_mfma_f32_16x16x16_bf16(a, b, c, 0, 0, 0);
#else
  asm volatile("v_mfma_f32_16x16x16_bf16 %0, %1, %2, %0\n\ts_nop 2"
               : "+v"(c) : "v"(a), "v"(b));
  return c;
#endif
}

// ---------- fused prep: cvt x -> bf16 | transpose Wq/Wk/Wv | cvt Wp ----------
__global__ __launch_bounds__(256) void prep(
    const float* __restrict__ x, u16* __restrict__ xbf,
    const float* __restrict__ Wq, const float* __restrict__ Wk,
    const float* __restrict__ Wv, u16* __restrict__ wt,
    const float* __restrict__ Wp, u16* __restrict__ wpbf) {
  const int tid = threadIdx.x;
  const int b = blockIdx.x;
  __shared__ __align__(16) u16 tile[64 * 72];
  if (b < 4096) {
    const size_t i = (size_t)b * 256 + tid;
    const float4* p = (const float4*)(x + i * 8);
    *(uint4*)(xbf + i * 8) = pack8(p[0], p[1]);
  } else if (b < 4864) {
    const int idx = b - 4096;
    const int w = idx >> 8;                 // which weight
    const int mat = (idx >> 4) & 15;        // head
    const int r0 = (idx & 15) * 64;         // row block
    const float* src = (w == 0 ? Wq : (w == 1 ? Wk : Wv)) + (size_t)mat * 1024 * 64;
    u16* dst = wt + (size_t)w * 1024 * 1024 + (size_t)mat * 1024 * 64;
#pragma unroll
    for (int i = 0; i < 2; ++i) {
      const int c = tid + i * 256;
      const int r = c >> 3, off = (c & 7) * 8;
      const float* p = src + (size_t)(r0 + r) * 64 + off;
      *(uint4*)(&tile[r * 72 + off]) = pack8(*(const float4*)p, *(const float4*)(p + 4));
    }
    __syncthreads();
#pragma unroll
    for (int i = 0; i < 2; ++i) {
      const int c = tid + i * 256;
      const int d = c >> 3, roff = (c & 7) * 8;
      bf16x8 v;
#pragma unroll
      for (int j = 0; j < 8; ++j) v[j] = (short)tile[(roff + j) * 72 + d];
      *(bf16x8*)(dst + (size_t)d * 1024 + r0 + roff) = v;
    }
  } else {
    const size_t i = (size_t)(b - 4864) * 256 + tid;
    const float4* p = (const float4*)(Wp + i * 8);
    *(uint4*)(wpbf + i * 8) = pack8(p[0], p[1]);
  }
}

// ---------- gemm_bt (bf16 operands, global_load_lds staging, m97 pattern) ----------
// MODE 0: o0=Q (PRE-SCALED by 0.125*log2e), o1=K as [B,H,T,D]; o2=V TRANSPOSED [B,H,D,T].
// MODE 1: fout[M,1024] FP32 + bias bp.
template <int MODE>
__global__ __launch_bounds__(256) void gemm_bt(
    const u16* __restrict__ A, const u16* __restrict__ BT,
    u16* __restrict__ o0, u16* __restrict__ o1, u16* __restrict__ o2,
    float* __restrict__ fout, const float* __restrict__ bp) {
  __shared__ __align__(16) u16 As[128 * 32];
  __shared__ __align__(16) u16 Bs[128 * 32];
  const int tid = threadIdx.x;
  const int lane = tid & 63, wv = tid >> 6;
  const int g = lane >> 4, ln = lane & 15;
  const int wm = wv >> 1, wn = wv & 1;
  const int m0 = blockIdx.x * 128, n0 = blockIdx.y * 128;

  const f32x4 fz = {0.f, 0.f, 0.f, 0.f};
  f32x4 acc[4][4];
#pragma unroll
  for (int i = 0; i < 4; ++i)
#pragma unroll
    for (int j = 0; j < 4; ++j) acc[i][j] = fz;

  for (int k0 = 0; k0 < 1024; k0 += 32) {
    __syncthreads();
#pragma unroll
    for (int i = 0; i < 2; ++i) {
      const int c = tid + i * 256;
      const int r = c >> 2, off = (c & 3) * 8;
      gload16(A + (size_t)(m0 + r) * 1024 + k0 + off, &As[c * 8]);
      gload16(BT + (size_t)(n0 + r) * 1024 + k0 + off, &Bs[c * 8]);
    }
    __syncthreads();
    bf16x8 af[4], bfr[4];
#pragma unroll
    for (int rt = 0; rt < 4; ++rt)
      af[rt] = *(const bf16x8*)(&As[(wm * 64 + rt * 16 + ln) * 32 + g * 8]);
#pragma unroll
    for (int ct = 0; ct < 4; ++ct)
      bfr[ct] = *(const bf16x8*)(&Bs[(wn * 64 + ct * 16 + ln) * 32 + g * 8]);
#pragma unroll
    for (int rt = 0; rt < 4; ++rt)
#pragma unroll
      for (int ct = 0; ct < 4; ++ct)
        acc[rt][ct] = __builtin_amdgcn_mfma_f32_16x16x32_bf16(af[rt], bfr[ct],
                                                              acc[rt][ct], 0, 0, 0);
  }

  if (MODE == 0) {
    const int which = n0 >> 10;
    const int nl0 = (n0 & 1023) + wn * 64;
    const float qs = (which == 0) ? 0.1803368801f : 1.0f;  // 0.125*log2(e) for Q
    if (which < 2) {
      u16* outp = which == 0 ? o0 : o1;
#pragma unroll
      for (int rt = 0; rt < 4; ++rt)
#pragma unroll
        for (int ct = 0; ct < 4; ++ct) {
          const int nl = nl0 + ct * 16 + ln;
          const int h = nl >> 6, d = nl & 63;
#pragma unroll
          for (int r = 0; r < 4; ++r) {
            const int m = m0 + wm * 64 + rt * 16 + 4 * g + r;
            const int b = m >> 11, t = m & 2047;
            outp[(((size_t)(b * 16 + h) * 2048 + t) << 6) + d] =
                f2bf(acc[rt][ct][r] * qs);
          }
        }
    } else {
#pragma unroll
      for (int rt = 0; rt < 4; ++rt) {
        const int tb = m0 + wm * 64 + rt * 16 + 4 * g;  // multiple of 4
        const int b = tb >> 11, t = tb & 2047;
#pragma unroll
        for (int ct = 0; ct < 4; ++ct) {
          const int nl = nl0 + ct * 16 + ln;
          const int h = nl >> 6, d = nl & 63;
          u16* dst = o2 + ((size_t)((b * 16 + h) * 64 + d) << 11) + t;
#pragma unroll
          for (int r = 0; r < 4; ++r) dst[r] = f2bf(acc[rt][ct][r]);
        }
      }
    }
  } else {
#pragma unroll
    for (int ct = 0; ct < 4; ++ct) {
      const int n = n0 + wn * 64 + ct * 16 + ln;
      const float bias = bp[n];
#pragma unroll
      for (int rt = 0; rt < 4; ++rt)
#pragma unroll
        for (int r = 0; r < 4; ++r) {
          const int m = m0 + wm * 64 + rt * 16 + 4 * g + r;
          fout[(size_t)m * 1024 + n] = acc[rt][ct][r] + bias;
        }
    }
  }
}

// ---------- flash attention v5: 128-row blocks (r7 density) + uniform pairing ----------
// 128-row q-segments (16 total). Block (bh, jb) runs segment jb then 15-jb ->
// exactly 34 staged k-tiles per block; grid (64,8) = 2 blocks/CU start-to-finish.
// S^T = K Q^T (C/D layout == 16x16x16 A-frag layout -> P stays in registers).
// Unnormalized softmax (Q pre-scaled by 0.125*log2e); l via ones-fragment MFMA.
// blockIdx.x = bh: all blocks of a head land on XCD bh%8 (K/V L2 locality).
__global__ __launch_bounds__(256) void attn_kernel(
    const u16* __restrict__ Q, const u16* __restrict__ K,
    const u16* __restrict__ VT, u16* __restrict__ AO) {
  const int tid = threadIdx.x;
  const int wv = tid >> 6, lane = tid & 63, g = lane >> 4, ln = lane & 15;
  const int bh = blockIdx.x;
  const int jb = blockIdx.y;
  const u16* Qb = Q + (size_t)bh * (2048 * 64);
  const u16* Kb = K + (size_t)bh * (2048 * 64);
  const u16* Vb = VT + (size_t)bh * (64 * 2048);

  __shared__ __align__(16) u16 Ks[64 * 72];
  __shared__ __align__(16) u16 Vs[64 * 72];

  const int sr0 = tid >> 3, so0 = (tid & 7) * 8;
  const int sr1 = sr0 + 32;

  // prefetch phase-0 tile 0
  uint4 kpf0 = *(const uint4*)(Kb + (size_t)sr0 * 64 + so0);
  uint4 kpf1 = *(const uint4*)(Kb + (size_t)sr1 * 64 + so0);
  uint4 vpf0 = *(const uint4*)(Vb + (size_t)sr0 * 2048 + so0);
  uint4 vpf1 = *(const uint4*)(Vb + (size_t)sr1 * 2048 + so0);

  const int b = bh >> 4, h = bh & 15;
  const short ob = 0x3F80;
  const bf16x4 ones = {ob, ob, ob, ob};
  const f32x4 fz = {0.f, 0.f, 0.f, 0.f};

#pragma unroll
  for (int ph = 0; ph < 2; ++ph) {
    const int qi = (ph == 0) ? jb : 15 - jb;
    const int q0 = qi * 128;
    const int nt = 2 * qi + 2;               // staged tiles this phase
    const int ntw = 2 * qi + 1 + (wv >> 1);  // this wave's compute tiles

    // Q fragments (MFMA B-operand): 2 row-tiles x 2 k-halves
    bf16x8 qa[2][2];
#pragma unroll
    for (int rt = 0; rt < 2; ++rt) {
      const int row = q0 + wv * 32 + rt * 16 + ln;
#pragma unroll
      for (int hh = 0; hh < 2; ++hh)
        qa[rt][hh] = *(const bf16x8*)(Qb + (size_t)row * 64 + hh * 32 + g * 8);
    }

    f32x4 oacc[2][4], lacc[2];
#pragma unroll
    for (int rt = 0; rt < 2; ++rt) {
      lacc[rt] = fz;
#pragma unroll
      for (int dt = 0; dt < 4; ++dt) oacc[rt][dt] = fz;
    }

    for (int kt = 0; kt < nt; ++kt) {
      __syncthreads();
      *(uint4*)(&Ks[sr0 * 72 + so0]) = kpf0;
      *(uint4*)(&Ks[sr1 * 72 + so0]) = kpf1;
      *(uint4*)(&Vs[sr0 * 72 + so0]) = vpf0;
      *(uint4*)(&Vs[sr1 * 72 + so0]) = vpf1;
      __syncthreads();
      // prefetch next tile (next kt, or tile 0 of phase B)
      if ((kt + 1 < nt) || (ph == 0)) {
        const int sn = (kt + 1 < nt) ? (kt + 1) * 64 : 0;
        kpf0 = *(const uint4*)(Kb + (size_t)(sn + sr0) * 64 + so0);
        kpf1 = *(const uint4*)(Kb + (size_t)(sn + sr1) * 64 + so0);
        vpf0 = *(const uint4*)(Vb + (size_t)sr0 * 2048 + sn + so0);
        vpf1 = *(const uint4*)(Vb + (size_t)sr1 * 2048 + sn + so0);
      }
      if (kt < ntw) {
        const int s0 = kt * 64;
        // S^T = K Q^T  (lane holds s = st*16+4g+r, q = q0+wv*32+rt*16+ln)
        f32x4 sfT[2][4];
#pragma unroll
        for (int rt = 0; rt < 2; ++rt)
#pragma unroll
          for (int st = 0; st < 4; ++st) sfT[rt][st] = fz;
#pragma unroll
        for (int st = 0; st < 4; ++st) {
          const bf16x8 kb0 = *(const bf16x8*)(&Ks[(st * 16 + ln) * 72 + g * 8]);
          const bf16x8 kb1 = *(const bf16x8*)(&Ks[(st * 16 + ln) * 72 + 32 + g * 8]);
#pragma unroll
          for (int rt = 0; rt < 2; ++rt) {
            sfT[rt][st] = __builtin_amdgcn_mfma_f32_16x16x32_bf16(kb0, qa[rt][0],
                                                                  sfT[rt][st], 0, 0, 0);
            sfT[rt][st] = __builtin_amdgcn_mfma_f32_16x16x32_bf16(kb1, qa[rt][1],
                                                                  sfT[rt][st], 0, 0, 0);
          }
        }
        // exp (Q pre-scaled); causal mask only on this wave's diagonal tile
        const bool diag = (kt == ntw - 1);
        bf16x4 pa[2][4];
#pragma unroll
        for (int rt = 0; rt < 2; ++rt) {
          const int qloc = wv * 32 + rt * 16 + ln;   // q - q0
#pragma unroll
          for (int st = 0; st < 4; ++st) {
            float e[4];
#pragma unroll
            for (int r = 0; r < 4; ++r) e[r] = __builtin_amdgcn_exp2f(sfT[rt][st][r]);
            if (diag) {
              const int sloc = s0 - q0 + st * 16 + 4 * g;  // s - q0
#pragma unroll
              for (int r = 0; r < 4; ++r)
                if (sloc + r > qloc) e[r] = 0.f;
            }
            uint2 packed = {cvt_pk(e[0], e[1]), cvt_pk(e[2], e[3])};
            pa[rt][st] = __builtin_bit_cast(bf16x4, packed);
          }
        }
        // O += P V ; l += P . ones
#pragma unroll
        for (int st = 0; st < 4; ++st) {
#pragma unroll
          for (int dt = 0; dt < 4; ++dt) {
            const bf16x4 vb =
                *(const bf16x4*)(&Vs[(dt * 16 + ln) * 72 + st * 16 + 4 * g]);
#pragma unroll
            for (int rt = 0; rt < 2; ++rt)
              oacc[rt][dt] = mfma16(pa[rt][st], vb, oacc[rt][dt]);
          }
#pragma unroll
          for (int rt = 0; rt < 2; ++rt)
            lacc[rt] = mfma16(pa[rt][st], ones, lacc[rt]);
        }
      }
    }
    // epilogue for this phase
#pragma unroll
    for (int rt = 0; rt < 2; ++rt) {
      float linv[4];
#pragma unroll
      for (int r = 0; r < 4; ++r) linv[r] = 1.f / lacc[rt][r];
#pragma unroll
      for (int dt = 0; dt < 4; ++dt)
#pragma unroll
        for (int r = 0; r < 4; ++r) {
          const int qg = q0 + wv * 32 + rt * 16 + 4 * g + r;
          AO[(size_t)(b * 2048 + qg) * 1024 + h * 64 + dt * 16 + ln] =
              f2bf(oacc[rt][dt][r] * linv[r]);
        }
    }
  }
}

// ---------- launch ----------
// Inputs FP32, output FP32; internal bf16. ws (72 MB):
//   [0,16M): xbf (phase 1) then AO (phase 2)
//   [16,22M): wt    [22,24M): wpbf
//   Q [24,40M)   K [40,56M)   VT [56,72M)
extern "C" void kernel_launch(void* const* d_in, const int* in_sizes, int n_in,
                              void* d_out, int out_size, void* d_ws, size_t ws_size,
                              hipStream_t stream) {
  const float* x  = (const float*)d_in[0];
  const float* Wq = (const float*)d_in[1];
  const float* Wk = (const float*)d_in[2];
  const float* Wv = (const float*)d_in[3];
  const float* Wp = (const float*)d_in[4];
  const float* bp = (const float*)d_in[5];
  float* out = (float*)d_out;

  char* ws = (char*)d_ws;
  const size_t MB = 1048576;
  u16* xbf  = (u16*)(ws);
  u16* aows = (u16*)(ws);
  u16* wt   = (u16*)(ws + 16 * MB);
  u16* wpbf = (u16*)(ws + 22 * MB);
  u16* qws  = (u16*)(ws + 24 * MB);
  u16* kws  = (u16*)(ws + 40 * MB);
  u16* vtws = (u16*)(ws + 56 * MB);

  // fused prep: x->bf16, Wq/Wk/Wv -> WT[3072][1024] bf16, Wp->bf16
  prep<<<dim3(5376), 256, 0, stream>>>(x, xbf, Wq, Wk, Wv, wt, Wp, wpbf);
  // QKV projection -> Q(prescaled),K [B,H,T,D]; V direct-transposed [B,H,D,T]
  gemm_bt<0><<<dim3(64, 24), 256, 0, stream>>>(xbf, wt, qws, kws, vtws,
                                               nullptr, nullptr);
  // causal flash attention -> AO [B,T,H*D] (overlays dead xbf)
  attn_kernel<<<dim3(64, 8), 256, 0, stream>>>(qws, kws, vtws, aows);
  // output projection: AO @ Wp^T + bp -> out FP32
  gemm_bt<1><<<dim3(64, 8), 256, 0, stream>>>(aows, wpbf, nullptr, nullptr,
                                              nullptr, out, bp);
}

// Round 10
// 266.888 us; speedup vs baseline: 1.0272x; 1.0048x over previous
//
#include <hip/hip_runtime.h>

typedef unsigned short u16;
typedef __attribute__((ext_vector_type(8))) short bf16x8;
typedef __attribute__((ext_vector_type(4))) short bf16x4;
typedef __attribute__((ext_vector_type(4))) float f32x4;

// ---------- helpers ----------
__device__ __forceinline__ u16 f2bf(float f) {
  unsigned u = __float_as_uint(f);
  u += 0x7FFFu + ((u >> 16) & 1u);   // RNE
  return (u16)(u >> 16);
}
__device__ __forceinline__ unsigned pack2(float a, float b) {
  return (unsigned)f2bf(a) | ((unsigned)f2bf(b) << 16);
}
#if __has_builtin(__builtin_amdgcn_cvt_pk_bf16_f32)
typedef __attribute__((ext_vector_type(2))) __bf16 bf16v2;
__device__ __forceinline__ unsigned cvt_pk(float a, float b) {
  bf16v2 v = __builtin_amdgcn_cvt_pk_bf16_f32(a, b);
  return __builtin_bit_cast(unsigned, v);
}
#else
__device__ __forceinline__ unsigned cvt_pk(float a, float b) { return pack2(a, b); }
#endif
__device__ __forceinline__ uint4 pack8(float4 a, float4 b) {
  uint4 r;
  r.x = cvt_pk(a.x, a.y); r.y = cvt_pk(a.z, a.w);
  r.z = cvt_pk(b.x, b.y); r.w = cvt_pk(b.z, b.w);
  return r;
}
__device__ __forceinline__ void gload16(const void* g, void* l) {
  __builtin_amdgcn_global_load_lds(
      (const __attribute__((address_space(1))) void*)g,
      (__attribute__((address_space(3))) void*)l, 16, 0, 0);
}
// 16x16x16 bf16 MFMA (A-frag layout == 16x16 C/D layout -> P stays in regs)
__device__ __forceinline__ f32x4 mfma16(bf16x4 a, bf16x4 b, f32x4 c) {
#if __has_builtin(__builtin_amdgcn_mfma_f32_16x16x16bf16_1k)
  return __builtin_amdgcn_mfma_f32_16x16x16bf16_1k(a, b, c, 0, 0, 0);
#elif __has_builtin(__builtin_amdgcn_mfma_f32_16x16x16_bf16)
  return __builtin_amdgcn_mfma_f32_16x16x16_bf16(a, b, c, 0, 0, 0);
#else
  asm volatile("v_mfma_f32_16x16x16_bf16 %0, %1, %2, %0\n\ts_nop 2"
               : "+v"(c) : "v"(a), "v"(b));
  return c;
#endif
}

// ---------- fused prep: cvt x -> bf16 | transpose Wq/Wk/Wv | cvt Wp ----------
__global__ __launch_bounds__(256) void prep(
    const float* __restrict__ x, u16* __restrict__ xbf,
    const float* __restrict__ Wq, const float* __restrict__ Wk,
    const float* __restrict__ Wv, u16* __restrict__ wt,
    const float* __restrict__ Wp, u16* __restrict__ wpbf) {
  const int tid = threadIdx.x;
  const int b = blockIdx.x;
  __shared__ __align__(16) u16 tile[64 * 72];
  if (b < 4096) {
    const size_t i = (size_t)b * 256 + tid;
    const float4* p = (const float4*)(x + i * 8);
    *(uint4*)(xbf + i * 8) = pack8(p[0], p[1]);
  } else if (b < 4864) {
    const int idx = b - 4096;
    const int w = idx >> 8;                 // which weight
    const int mat = (idx >> 4) & 15;        // head
    const int r0 = (idx & 15) * 64;         // row block
    const float* src = (w == 0 ? Wq : (w == 1 ? Wk : Wv)) + (size_t)mat * 1024 * 64;
    u16* dst = wt + (size_t)w * 1024 * 1024 + (size_t)mat * 1024 * 64;
#pragma unroll
    for (int i = 0; i < 2; ++i) {
      const int c = tid + i * 256;
      const int r = c >> 3, off = (c & 7) * 8;
      const float* p = src + (size_t)(r0 + r) * 64 + off;
      *(uint4*)(&tile[r * 72 + off]) = pack8(*(const float4*)p, *(const float4*)(p + 4));
    }
    __syncthreads();
#pragma unroll
    for (int i = 0; i < 2; ++i) {
      const int c = tid + i * 256;
      const int d = c >> 3, roff = (c & 7) * 8;
      bf16x8 v;
#pragma unroll
      for (int j = 0; j < 8; ++j) v[j] = (short)tile[(roff + j) * 72 + d];
      *(bf16x8*)(dst + (size_t)d * 1024 + r0 + roff) = v;
    }
  } else {
    const size_t i = (size_t)(b - 4864) * 256 + tid;
    const float4* p = (const float4*)(Wp + i * 8);
    *(uint4*)(wpbf + i * 8) = pack8(p[0], p[1]);
  }
}

// ---------- gemm_bt (bf16 operands, global_load_lds staging, m97 pattern) ----------
// MODE 0: o0=Q (PRE-SCALED by 0.125*log2e), o1=K as [B,H,T,D]; o2=V TRANSPOSED [B,H,D,T].
// MODE 1: fout[M,1024] FP32 + bias bp.
template <int MODE>
__global__ __launch_bounds__(256) void gemm_bt(
    const u16* __restrict__ A, const u16* __restrict__ BT,
    u16* __restrict__ o0, u16* __restrict__ o1, u16* __restrict__ o2,
    float* __restrict__ fout, const float* __restrict__ bp) {
  __shared__ __align__(16) u16 As[128 * 32];
  __shared__ __align__(16) u16 Bs[128 * 32];
  const int tid = threadIdx.x;
  const int lane = tid & 63, wv = tid >> 6;
  const int g = lane >> 4, ln = lane & 15;
  const int wm = wv >> 1, wn = wv & 1;
  const int m0 = blockIdx.x * 128, n0 = blockIdx.y * 128;

  const f32x4 fz = {0.f, 0.f, 0.f, 0.f};
  f32x4 acc[4][4];
#pragma unroll
  for (int i = 0; i < 4; ++i)
#pragma unroll
    for (int j = 0; j < 4; ++j) acc[i][j] = fz;

  for (int k0 = 0; k0 < 1024; k0 += 32) {
    __syncthreads();
#pragma unroll
    for (int i = 0; i < 2; ++i) {
      const int c = tid + i * 256;
      const int r = c >> 2, off = (c & 3) * 8;
      gload16(A + (size_t)(m0 + r) * 1024 + k0 + off, &As[c * 8]);
      gload16(BT + (size_t)(n0 + r) * 1024 + k0 + off, &Bs[c * 8]);
    }
    __syncthreads();
    bf16x8 af[4], bfr[4];
#pragma unroll
    for (int rt = 0; rt < 4; ++rt)
      af[rt] = *(const bf16x8*)(&As[(wm * 64 + rt * 16 + ln) * 32 + g * 8]);
#pragma unroll
    for (int ct = 0; ct < 4; ++ct)
      bfr[ct] = *(const bf16x8*)(&Bs[(wn * 64 + ct * 16 + ln) * 32 + g * 8]);
#pragma unroll
    for (int rt = 0; rt < 4; ++rt)
#pragma unroll
      for (int ct = 0; ct < 4; ++ct)
        acc[rt][ct] = __builtin_amdgcn_mfma_f32_16x16x32_bf16(af[rt], bfr[ct],
                                                              acc[rt][ct], 0, 0, 0);
  }

  if (MODE == 0) {
    const int which = n0 >> 10;
    const int nl0 = (n0 & 1023) + wn * 64;
    const float qs = (which == 0) ? 0.1803368801f : 1.0f;  // 0.125*log2(e) for Q
    if (which < 2) {
      u16* outp = which == 0 ? o0 : o1;
#pragma unroll
      for (int rt = 0; rt < 4; ++rt)
#pragma unroll
        for (int ct = 0; ct < 4; ++ct) {
          const int nl = nl0 + ct * 16 + ln;
          const int h = nl >> 6, d = nl & 63;
          const unsigned p01 = cvt_pk(acc[rt][ct][0] * qs, acc[rt][ct][1] * qs);
          const unsigned p23 = cvt_pk(acc[rt][ct][2] * qs, acc[rt][ct][3] * qs);
          const u16 vv[4] = {(u16)p01, (u16)(p01 >> 16), (u16)p23, (u16)(p23 >> 16)};
#pragma unroll
          for (int r = 0; r < 4; ++r) {
            const int m = m0 + wm * 64 + rt * 16 + 4 * g + r;
            const int b = m >> 11, t = m & 2047;
            outp[(((size_t)(b * 16 + h) * 2048 + t) << 6) + d] = vv[r];
          }
        }
    } else {
      // V transposed [B,H,D,T]: 4 consecutive t per (rt,ct) -> one uint2 store
#pragma unroll
      for (int rt = 0; rt < 4; ++rt) {
        const int tb = m0 + wm * 64 + rt * 16 + 4 * g;  // multiple of 4
        const int b = tb >> 11, t = tb & 2047;
#pragma unroll
        for (int ct = 0; ct < 4; ++ct) {
          const int nl = nl0 + ct * 16 + ln;
          const int h = nl >> 6, d = nl & 63;
          uint2 pv;
          pv.x = cvt_pk(acc[rt][ct][0], acc[rt][ct][1]);
          pv.y = cvt_pk(acc[rt][ct][2], acc[rt][ct][3]);
          *(uint2*)(o2 + ((size_t)((b * 16 + h) * 64 + d) << 11) + t) = pv;
        }
      }
    }
  } else {
#pragma unroll
    for (int ct = 0; ct < 4; ++ct) {
      const int n = n0 + wn * 64 + ct * 16 + ln;
      const float bias = bp[n];
#pragma unroll
      for (int rt = 0; rt < 4; ++rt)
#pragma unroll
        for (int r = 0; r < 4; ++r) {
          const int m = m0 + wm * 64 + rt * 16 + 4 * g + r;
          fout[(size_t)m * 1024 + n] = acc[rt][ct][r] + bias;
        }
    }
  }
}

// ---------- flash attention v6: dbuf LDS, 1 barrier/tile, uniform pairing ----------
// 128-row q-segments (16). Block (bh,jb) runs segment jb then 15-jb: 34 staged
// k-tiles total (uniform). LDS double-buffered (stage g -> buf g&1); k-loop
// unrolled x2 (nt always even) so buffer indices are static and addresses hoist.
// S^T = K Q^T (C/D == 16x16x16 A-frag layout -> P stays in registers).
// Unnormalized softmax (Q pre-scaled); l via ones-fragment MFMA.
__global__ __launch_bounds__(256) void attn_kernel(
    const u16* __restrict__ Q, const u16* __restrict__ K,
    const u16* __restrict__ VT, u16* __restrict__ AO) {
  const int tid = threadIdx.x;
  const int wv = tid >> 6, lane = tid & 63, g = lane >> 4, ln = lane & 15;
  const int bh = blockIdx.x;
  const int jb = blockIdx.y;
  const u16* Qb = Q + (size_t)bh * (2048 * 64);
  const u16* Kb = K + (size_t)bh * (2048 * 64);
  const u16* Vb = VT + (size_t)bh * (64 * 2048);

  __shared__ __align__(16) u16 Ks[2][64 * 72];
  __shared__ __align__(16) u16 Vs[2][64 * 72];

  const int sr0 = tid >> 3, so0 = (tid & 7) * 8;
  const int wK0 = sr0 * 72 + so0, wK1 = (sr0 + 32) * 72 + so0;  // LDS write offs
  const size_t lK0 = (size_t)sr0 * 64 + so0, lK1 = (size_t)(sr0 + 32) * 64 + so0;
  const size_t lV0 = (size_t)sr0 * 2048 + so0, lV1 = (size_t)(sr0 + 32) * 2048 + so0;

  const int ntA = 2 * jb + 2;  // phase-A staged tiles; stages >= ntA are phase B

  // preload stage 0, write buf0, preload stage 1 into regs
  uint4 kpf0 = *(const uint4*)(Kb + lK0);
  uint4 kpf1 = *(const uint4*)(Kb + lK1);
  uint4 vpf0 = *(const uint4*)(Vb + lV0);
  uint4 vpf1 = *(const uint4*)(Vb + lV1);
  *(uint4*)(&Ks[0][wK0]) = kpf0;
  *(uint4*)(&Ks[0][wK1]) = kpf1;
  *(uint4*)(&Vs[0][wK0]) = vpf0;
  *(uint4*)(&Vs[0][wK1]) = vpf1;
  {
    const int s1 = (1 < ntA ? 1 : 1 - ntA) * 64;
    kpf0 = *(const uint4*)(Kb + (size_t)s1 * 64 + lK0);
    kpf1 = *(const uint4*)(Kb + (size_t)s1 * 64 + lK1);
    vpf0 = *(const uint4*)(Vb + s1 + lV0);
    vpf1 = *(const uint4*)(Vb + s1 + lV1);
  }

  const int b = bh >> 4, h = bh & 15;
  const short ob = 0x3F80;
  const bf16x4 ones = {ob, ob, ob, ob};
  const f32x4 fz = {0.f, 0.f, 0.f, 0.f};
  int gbase = 0;

#define ATTN_STEP(KT, BB)                                                      \
  {                                                                            \
    __syncthreads();                                                           \
    const int g1 = gbase + (KT) + 1;                                           \
    if (g1 < 34) { /* write stage g1 -> buf (BB^1) */                          \
      *(uint4*)(&Ks[(BB) ^ 1][wK0]) = kpf0;                                    \
      *(uint4*)(&Ks[(BB) ^ 1][wK1]) = kpf1;                                    \
      *(uint4*)(&Vs[(BB) ^ 1][wK0]) = vpf0;                                    \
      *(uint4*)(&Vs[(BB) ^ 1][wK1]) = vpf1;                                    \
    }                                                                          \
    const int g2 = gbase + (KT) + 2;                                           \
    if (g2 < 34) { /* prefetch stage g2 into regs */                           \
      const int sn = (g2 < ntA ? g2 : g2 - ntA) * 64;                          \
      kpf0 = *(const uint4*)(Kb + (size_t)sn * 64 + lK0);                      \
      kpf1 = *(const uint4*)(Kb + (size_t)sn * 64 + lK1);                      \
      vpf0 = *(const uint4*)(Vb + sn + lV0);                                   \
      vpf1 = *(const uint4*)(Vb + sn + lV1);                                   \
    }                                                                          \
    if ((KT) < ntw) {                                                          \
      f32x4 sfT[2][4];                                                         \
      _Pragma("unroll") for (int rt = 0; rt < 2; ++rt)                         \
          _Pragma("unroll") for (int st = 0; st < 4; ++st) sfT[rt][st] = fz;   \
      _Pragma("unroll") for (int st = 0; st < 4; ++st) {                       \
        const bf16x8 kb0 =                                                     \
            *(const bf16x8*)(&Ks[BB][(st * 16 + ln) * 72 + g * 8]);            \
        const bf16x8 kb1 =                                                     \
            *(const bf16x8*)(&Ks[BB][(st * 16 + ln) * 72 + 32 + g * 8]);       \
        _Pragma("unroll") for (int rt = 0; rt < 2; ++rt) {                     \
          sfT[rt][st] = __builtin_amdgcn_mfma_f32_16x16x32_bf16(               \
              kb0, qa[rt][0], sfT[rt][st], 0, 0, 0);                           \
          sfT[rt][st] = __builtin_amdgcn_mfma_f32_16x16x32_bf16(               \
              kb1, qa[rt][1], sfT[rt][st], 0, 0, 0);                           \
        }                                                                      \
      }                                                                        \
      const bool diag = ((KT) == ntw - 1);                                     \
      const int s0q = (KT)*64 - q0;                                            \
      bf16x4 pa[2][4];                                                         \
      _Pragma("unroll") for (int rt = 0; rt < 2; ++rt) {                       \
        const int qloc = wv * 32 + rt * 16 + ln;                               \
        _Pragma("unroll") for (int st = 0; st < 4; ++st) {                     \
          float e[4];                                                          \
          _Pragma("unroll") for (int r = 0; r < 4; ++r)                        \
              e[r] = __builtin_amdgcn_exp2f(sfT[rt][st][r]);                   \
          if (diag) {                                                          \
            const int sloc = s0q + st * 16 + 4 * g;                            \
            _Pragma("unroll") for (int r = 0; r < 4; ++r)                      \
                if (sloc + r > qloc) e[r] = 0.f;                               \
          }                                                                    \
          uint2 packed = {cvt_pk(e[0], e[1]), cvt_pk(e[2], e[3])};             \
          pa[rt][st] = __builtin_bit_cast(bf16x4, packed);                     \
        }                                                                      \
      }                                                                        \
      _Pragma("unroll") for (int st = 0; st < 4; ++st) {                       \
        _Pragma("unroll") for (int dt = 0; dt < 4; ++dt) {                     \
          const bf16x4 vb = *(const bf16x4*)(                                  \
              &Vs[BB][(dt * 16 + ln) * 72 + st * 16 + 4 * g]);                 \
          _Pragma("unroll") for (int rt = 0; rt < 2; ++rt)                     \
              oacc[rt][dt] = mfma16(pa[rt][st], vb, oacc[rt][dt]);             \
        }                                                                      \
        _Pragma("unroll") for (int rt = 0; rt < 2; ++rt)                       \
            lacc[rt] = mfma16(pa[rt][st], ones, lacc[rt]);                     \
      }                                                                        \
    }                                                                          \
  }

#pragma unroll
  for (int ph = 0; ph < 2; ++ph) {
    const int qi = (ph == 0) ? jb : 15 - jb;
    const int q0 = qi * 128;
    const int nt = 2 * qi + 2;               // even
    const int ntw = 2 * qi + 1 + (wv >> 1);  // this wave's compute tiles

    bf16x8 qa[2][2];
#pragma unroll
    for (int rt = 0; rt < 2; ++rt) {
      const int row = q0 + wv * 32 + rt * 16 + ln;
#pragma unroll
      for (int hh = 0; hh < 2; ++hh)
        qa[rt][hh] = *(const bf16x8*)(Qb + (size_t)row * 64 + hh * 32 + g * 8);
    }
    f32x4 oacc[2][4], lacc[2];
#pragma unroll
    for (int rt = 0; rt < 2; ++rt) {
      lacc[rt] = fz;
#pragma unroll
      for (int dt = 0; dt < 4; ++dt) oacc[rt][dt] = fz;
    }

    for (int kt = 0; kt < nt; kt += 2) {
      ATTN_STEP(kt, 0);
      ATTN_STEP(kt + 1, 1);
    }
    gbase += nt;

    // epilogue for this phase
#pragma unroll
    for (int rt = 0; rt < 2; ++rt) {
      float linv[4];
#pragma unroll
      for (int r = 0; r < 4; ++r) linv[r] = 1.f / lacc[rt][r];
#pragma unroll
      for (int dt = 0; dt < 4; ++dt) {
        const unsigned p01 =
            cvt_pk(oacc[rt][dt][0] * linv[0], oacc[rt][dt][1] * linv[1]);
        const unsigned p23 =
            cvt_pk(oacc[rt][dt][2] * linv[2], oacc[rt][dt][3] * linv[3]);
        const u16 vv[4] = {(u16)p01, (u16)(p01 >> 16), (u16)p23, (u16)(p23 >> 16)};
#pragma unroll
        for (int r = 0; r < 4; ++r) {
          const int qg = q0 + wv * 32 + rt * 16 + 4 * g + r;
          AO[(size_t)(b * 2048 + qg) * 1024 + h * 64 + dt * 16 + ln] = vv[r];
        }
      }
    }
  }
#undef ATTN_STEP
}

// ---------- launch ----------
// Inputs FP32, output FP32; internal bf16. ws (72 MB):
//   [0,16M): xbf (phase 1) then AO (phase 2)
//   [16,22M): wt    [22,24M): wpbf
//   Q [24,40M)   K [40,56M)   VT [56,72M)
extern "C" void kernel_launch(void* const* d_in, const int* in_sizes, int n_in,
                              void* d_out, int out_size, void* d_ws, size_t ws_size,
                              hipStream_t stream) {
  const float* x  = (const float*)d_in[0];
  const float* Wq = (const float*)d_in[1];
  const float* Wk = (const float*)d_in[2];
  const float* Wv = (const float*)d_in[3];
  const float* Wp = (const float*)d_in[4];
  const float* bp = (const float*)d_in[5];
  float* out = (float*)d_out;

  char* ws = (char*)d_ws;
  const size_t MB = 1048576;
  u16* xbf  = (u16*)(ws);
  u16* aows = (u16*)(ws);
  u16* wt   = (u16*)(ws + 16 * MB);
  u16* wpbf = (u16*)(ws + 22 * MB);
  u16* qws  = (u16*)(ws + 24 * MB);
  u16* kws  = (u16*)(ws + 40 * MB);
  u16* vtws = (u16*)(ws + 56 * MB);

  // fused prep: x->bf16, Wq/Wk/Wv -> WT[3072][1024] bf16, Wp->bf16
  prep<<<dim3(5376), 256, 0, stream>>>(x, xbf, Wq, Wk, Wv, wt, Wp, wpbf);
  // QKV projection -> Q(prescaled),K [B,H,T,D]; V direct-transposed [B,H,D,T]
  gemm_bt<0><<<dim3(64, 24), 256, 0, stream>>>(xbf, wt, qws, kws, vtws,
                                               nullptr, nullptr);
  // causal flash attention -> AO [B,T,H*D] (overlays dead xbf)
  attn_kernel<<<dim3(64, 8), 256, 0, stream>>>(qws, kws, vtws, aows);
  // output projection: AO @ Wp^T + bp -> out FP32
  gemm_bt<1><<<dim3(64, 8), 256, 0, stream>>>(aows, wpbf, nullptr, nullptr,
                                              nullptr, out, bp);
}

// Round 11
// 263.356 us; speedup vs baseline: 1.0410x; 1.0134x over previous
//
#include <hip/hip_runtime.h>

typedef unsigned short u16;
typedef __attribute__((ext_vector_type(8))) short bf16x8;
typedef __attribute__((ext_vector_type(4))) short bf16x4;
typedef __attribute__((ext_vector_type(4))) float f32x4;

// ---------- helpers ----------
__device__ __forceinline__ u16 f2bf(float f) {
  unsigned u = __float_as_uint(f);
  u += 0x7FFFu + ((u >> 16) & 1u);   // RNE
  return (u16)(u >> 16);
}
__device__ __forceinline__ unsigned pack2(float a, float b) {
  return (unsigned)f2bf(a) | ((unsigned)f2bf(b) << 16);
}
#if __has_builtin(__builtin_amdgcn_cvt_pk_bf16_f32)
typedef __attribute__((ext_vector_type(2))) __bf16 bf16v2;
__device__ __forceinline__ unsigned cvt_pk(float a, float b) {
  bf16v2 v = __builtin_amdgcn_cvt_pk_bf16_f32(a, b);
  return __builtin_bit_cast(unsigned, v);
}
#else
__device__ __forceinline__ unsigned cvt_pk(float a, float b) { return pack2(a, b); }
#endif
__device__ __forceinline__ uint4 pack8(float4 a, float4 b) {
  uint4 r;
  r.x = cvt_pk(a.x, a.y); r.y = cvt_pk(a.z, a.w);
  r.z = cvt_pk(b.x, b.y); r.w = cvt_pk(b.z, b.w);
  return r;
}
__device__ __forceinline__ void gload16(const void* g, void* l) {
  __builtin_amdgcn_global_load_lds(
      (const __attribute__((address_space(1))) void*)g,
      (__attribute__((address_space(3))) void*)l, 16, 0, 0);
}
// 16x16x16 bf16 MFMA (A-frag layout == 16x16 C/D layout -> P stays in regs)
__device__ __forceinline__ f32x4 mfma16(bf16x4 a, bf16x4 b, f32x4 c) {
#if __has_builtin(__builtin_amdgcn_mfma_f32_16x16x16bf16_1k)
  return __builtin_amdgcn_mfma_f32_16x16x16bf16_1k(a, b, c, 0, 0, 0);
#elif __has_builtin(__builtin_amdgcn_mfma_f32_16x16x16_bf16)
  return __builtin_amdgcn_mfma_f32_16x16x16_bf16(a, b, c, 0, 0, 0);
#else
  asm volatile("v_mfma_f32_16x16x16_bf16 %0, %1, %2, %0\n\ts_nop 2"
               : "+v"(c) : "v"(a), "v"(b));
  return c;
#endif
}

// ---------- fused prep: cvt x -> bf16 | transpose Wq/Wk/Wv | cvt Wp ----------
__global__ __launch_bounds__(256) void prep(
    const float* __restrict__ x, u16* __restrict__ xbf,
    const float* __restrict__ Wq, const float* __restrict__ Wk,
    const float* __restrict__ Wv, u16* __restrict__ wt,
    const float* __restrict__ Wp, u16* __restrict__ wpbf) {
  const int tid = threadIdx.x;
  const int b = blockIdx.x;
  __shared__ __align__(16) u16 tile[64 * 72];
  if (b < 4096) {
    const size_t i = (size_t)b * 256 + tid;
    const float4* p = (const float4*)(x + i * 8);
    *(uint4*)(xbf + i * 8) = pack8(p[0], p[1]);
  } else if (b < 4864) {
    const int idx = b - 4096;
    const int w = idx >> 8;                 // which weight
    const int mat = (idx >> 4) & 15;        // head
    const int r0 = (idx & 15) * 64;         // row block
    const float* src = (w == 0 ? Wq : (w == 1 ? Wk : Wv)) + (size_t)mat * 1024 * 64;
    u16* dst = wt + (size_t)w * 1024 * 1024 + (size_t)mat * 1024 * 64;
#pragma unroll
    for (int i = 0; i < 2; ++i) {
      const int c = tid + i * 256;
      const int r = c >> 3, off = (c & 7) * 8;
      const float* p = src + (size_t)(r0 + r) * 64 + off;
      *(uint4*)(&tile[r * 72 + off]) = pack8(*(const float4*)p, *(const float4*)(p + 4));
    }
    __syncthreads();
#pragma unroll
    for (int i = 0; i < 2; ++i) {
      const int c = tid + i * 256;
      const int d = c >> 3, roff = (c & 7) * 8;
      bf16x8 v;
#pragma unroll
      for (int j = 0; j < 8; ++j) v[j] = (short)tile[(roff + j) * 72 + d];
      *(bf16x8*)(dst + (size_t)d * 1024 + r0 + roff) = v;
    }
  } else {
    const size_t i = (size_t)(b - 4864) * 256 + tid;
    const float4* p = (const float4*)(Wp + i * 8);
    *(uint4*)(wpbf + i * 8) = pack8(p[0], p[1]);
  }
}

// ---------- gemm_bt: BK=64 (half the barriers of m97's BK=32) ----------
// Staging uses two unpadded 128x32 half-planes per matrix so each
// global_load_lds keeps wave-contiguous LDS dests AND fragment reads keep the
// m97-proven conflict-free pattern.
// MODE 0: o0=Q (PRE-SCALED by 0.125*log2e), o1=K as [B,H,T,D]; o2=V TRANSPOSED [B,H,D,T].
// MODE 1: fout[M,1024] FP32 + bias bp.
template <int MODE>
__global__ __launch_bounds__(256) void gemm_bt(
    const u16* __restrict__ A, const u16* __restrict__ BT,
    u16* __restrict__ o0, u16* __restrict__ o1, u16* __restrict__ o2,
    float* __restrict__ fout, const float* __restrict__ bp) {
  __shared__ __align__(16) u16 As[2][128 * 32];
  __shared__ __align__(16) u16 Bs[2][128 * 32];
  const int tid = threadIdx.x;
  const int lane = tid & 63, wv = tid >> 6;
  const int g = lane >> 4, ln = lane & 15;
  const int wm = wv >> 1, wn = wv & 1;
  const int m0 = blockIdx.x * 128, n0 = blockIdx.y * 128;

  const f32x4 fz = {0.f, 0.f, 0.f, 0.f};
  f32x4 acc[4][4];
#pragma unroll
  for (int i = 0; i < 4; ++i)
#pragma unroll
    for (int j = 0; j < 4; ++j) acc[i][j] = fz;

  for (int k0 = 0; k0 < 1024; k0 += 64) {
    __syncthreads();
#pragma unroll
    for (int hf = 0; hf < 2; ++hf)
#pragma unroll
      for (int j = 0; j < 2; ++j) {
        const int c = j * 256 + tid;          // 0..511
        const int r = c >> 2, off = (c & 3) * 8;
        gload16(A + (size_t)(m0 + r) * 1024 + k0 + hf * 32 + off, &As[hf][c * 8]);
        gload16(BT + (size_t)(n0 + r) * 1024 + k0 + hf * 32 + off, &Bs[hf][c * 8]);
      }
    __syncthreads();
#pragma unroll
    for (int hf = 0; hf < 2; ++hf) {
      bf16x8 af[4], bfr[4];
#pragma unroll
      for (int rt = 0; rt < 4; ++rt)
        af[rt] = *(const bf16x8*)(&As[hf][(wm * 64 + rt * 16 + ln) * 32 + g * 8]);
#pragma unroll
      for (int ct = 0; ct < 4; ++ct)
        bfr[ct] = *(const bf16x8*)(&Bs[hf][(wn * 64 + ct * 16 + ln) * 32 + g * 8]);
#pragma unroll
      for (int rt = 0; rt < 4; ++rt)
#pragma unroll
        for (int ct = 0; ct < 4; ++ct)
          acc[rt][ct] = __builtin_amdgcn_mfma_f32_16x16x32_bf16(af[rt], bfr[ct],
                                                                acc[rt][ct], 0, 0, 0);
    }
  }

  if (MODE == 0) {
    const int which = n0 >> 10;
    const int nl0 = (n0 & 1023) + wn * 64;
    const float qs = (which == 0) ? 0.1803368801f : 1.0f;  // 0.125*log2(e) for Q
    if (which < 2) {
      u16* outp = which == 0 ? o0 : o1;
#pragma unroll
      for (int rt = 0; rt < 4; ++rt)
#pragma unroll
        for (int ct = 0; ct < 4; ++ct) {
          const int nl = nl0 + ct * 16 + ln;
          const int h = nl >> 6, d = nl & 63;
          const unsigned p01 = cvt_pk(acc[rt][ct][0] * qs, acc[rt][ct][1] * qs);
          const unsigned p23 = cvt_pk(acc[rt][ct][2] * qs, acc[rt][ct][3] * qs);
          const u16 vv[4] = {(u16)p01, (u16)(p01 >> 16), (u16)p23, (u16)(p23 >> 16)};
#pragma unroll
          for (int r = 0; r < 4; ++r) {
            const int m = m0 + wm * 64 + rt * 16 + 4 * g + r;
            const int b = m >> 11, t = m & 2047;
            outp[(((size_t)(b * 16 + h) * 2048 + t) << 6) + d] = vv[r];
          }
        }
    } else {
      // V transposed [B,H,D,T]: 4 consecutive t per (rt,ct) -> one uint2 store
#pragma unroll
      for (int rt = 0; rt < 4; ++rt) {
        const int tb = m0 + wm * 64 + rt * 16 + 4 * g;  // multiple of 4
        const int b = tb >> 11, t = tb & 2047;
#pragma unroll
        for (int ct = 0; ct < 4; ++ct) {
          const int nl = nl0 + ct * 16 + ln;
          const int h = nl >> 6, d = nl & 63;
          uint2 pv;
          pv.x = cvt_pk(acc[rt][ct][0], acc[rt][ct][1]);
          pv.y = cvt_pk(acc[rt][ct][2], acc[rt][ct][3]);
          *(uint2*)(o2 + ((size_t)((b * 16 + h) * 64 + d) << 11) + t) = pv;
        }
      }
    }
  } else {
#pragma unroll
    for (int ct = 0; ct < 4; ++ct) {
      const int n = n0 + wn * 64 + ct * 16 + ln;
      const float bias = bp[n];
#pragma unroll
      for (int rt = 0; rt < 4; ++rt)
#pragma unroll
        for (int r = 0; r < 4; ++r) {
          const int m = m0 + wm * 64 + rt * 16 + 4 * g + r;
          fout[(size_t)m * 1024 + n] = acc[rt][ct][r] + bias;
        }
    }
  }
}

// ---------- flash attention (r9 structure, proven 81.9us) ----------
// 128-row q-segments (16). Block (bh,jb) runs segment jb then 15-jb: 34 staged
// k-tiles per block (uniform). Single-buffer LDS, 2 barriers/tile (dbuf was
// tried r10: regressed — m99/m100 class). S^T = K Q^T (C/D == 16x16x16 A-frag
// layout -> P stays in registers). Unnormalized softmax (Q pre-scaled);
// l via ones-fragment MFMA. blockIdx.x = bh -> XCD bh%8 K/V locality.
__global__ __launch_bounds__(256) void attn_kernel(
    const u16* __restrict__ Q, const u16* __restrict__ K,
    const u16* __restrict__ VT, u16* __restrict__ AO) {
  const int tid = threadIdx.x;
  const int wv = tid >> 6, lane = tid & 63, g = lane >> 4, ln = lane & 15;
  const int bh = blockIdx.x;
  const int jb = blockIdx.y;
  const u16* Qb = Q + (size_t)bh * (2048 * 64);
  const u16* Kb = K + (size_t)bh * (2048 * 64);
  const u16* Vb = VT + (size_t)bh * (64 * 2048);

  __shared__ __align__(16) u16 Ks[64 * 72];
  __shared__ __align__(16) u16 Vs[64 * 72];

  const int sr0 = tid >> 3, so0 = (tid & 7) * 8;
  const int sr1 = sr0 + 32;

  // prefetch phase-0 tile 0
  uint4 kpf0 = *(const uint4*)(Kb + (size_t)sr0 * 64 + so0);
  uint4 kpf1 = *(const uint4*)(Kb + (size_t)sr1 * 64 + so0);
  uint4 vpf0 = *(const uint4*)(Vb + (size_t)sr0 * 2048 + so0);
  uint4 vpf1 = *(const uint4*)(Vb + (size_t)sr1 * 2048 + so0);

  const int b = bh >> 4, h = bh & 15;
  const short ob = 0x3F80;
  const bf16x4 ones = {ob, ob, ob, ob};
  const f32x4 fz = {0.f, 0.f, 0.f, 0.f};

#pragma unroll
  for (int ph = 0; ph < 2; ++ph) {
    const int qi = (ph == 0) ? jb : 15 - jb;
    const int q0 = qi * 128;
    const int nt = 2 * qi + 2;               // staged tiles this phase
    const int ntw = 2 * qi + 1 + (wv >> 1);  // this wave's compute tiles

    // Q fragments (MFMA B-operand): 2 row-tiles x 2 k-halves
    bf16x8 qa[2][2];
#pragma unroll
    for (int rt = 0; rt < 2; ++rt) {
      const int row = q0 + wv * 32 + rt * 16 + ln;
#pragma unroll
      for (int hh = 0; hh < 2; ++hh)
        qa[rt][hh] = *(const bf16x8*)(Qb + (size_t)row * 64 + hh * 32 + g * 8);
    }

    f32x4 oacc[2][4], lacc[2];
#pragma unroll
    for (int rt = 0; rt < 2; ++rt) {
      lacc[rt] = fz;
#pragma unroll
      for (int dt = 0; dt < 4; ++dt) oacc[rt][dt] = fz;
    }

    for (int kt = 0; kt < nt; ++kt) {
      __syncthreads();
      *(uint4*)(&Ks[sr0 * 72 + so0]) = kpf0;
      *(uint4*)(&Ks[sr1 * 72 + so0]) = kpf1;
      *(uint4*)(&Vs[sr0 * 72 + so0]) = vpf0;
      *(uint4*)(&Vs[sr1 * 72 + so0]) = vpf1;
      __syncthreads();
      // prefetch next tile (next kt, or tile 0 of phase B)
      if ((kt + 1 < nt) || (ph == 0)) {
        const int sn = (kt + 1 < nt) ? (kt + 1) * 64 : 0;
        kpf0 = *(const uint4*)(Kb + (size_t)(sn + sr0) * 64 + so0);
        kpf1 = *(const uint4*)(Kb + (size_t)(sn + sr1) * 64 + so0);
        vpf0 = *(const uint4*)(Vb + (size_t)sr0 * 2048 + sn + so0);
        vpf1 = *(const uint4*)(Vb + (size_t)sr1 * 2048 + sn + so0);
      }
      if (kt < ntw) {
        const int s0 = kt * 64;
        // S^T = K Q^T (first MFMA consumes fz directly: no acc zero-init)
        f32x4 sfT[2][4];
#pragma unroll
        for (int st = 0; st < 4; ++st) {
          const bf16x8 kb0 = *(const bf16x8*)(&Ks[(st * 16 + ln) * 72 + g * 8]);
          const bf16x8 kb1 = *(const bf16x8*)(&Ks[(st * 16 + ln) * 72 + 32 + g * 8]);
#pragma unroll
          for (int rt = 0; rt < 2; ++rt) {
            sfT[rt][st] = __builtin_amdgcn_mfma_f32_16x16x32_bf16(kb0, qa[rt][0],
                                                                  fz, 0, 0, 0);
            sfT[rt][st] = __builtin_amdgcn_mfma_f32_16x16x32_bf16(kb1, qa[rt][1],
                                                                  sfT[rt][st], 0, 0, 0);
          }
        }
        // exp (Q pre-scaled); causal mask only on this wave's diagonal tile
        const bool diag = (kt == ntw - 1);
        bf16x4 pa[2][4];
#pragma unroll
        for (int rt = 0; rt < 2; ++rt) {
          const int qloc = wv * 32 + rt * 16 + ln;   // q - q0
#pragma unroll
          for (int st = 0; st < 4; ++st) {
            float e[4];
#pragma unroll
            for (int r = 0; r < 4; ++r) e[r] = __builtin_amdgcn_exp2f(sfT[rt][st][r]);
            if (diag) {
              const int sloc = s0 - q0 + st * 16 + 4 * g;  // s - q0
#pragma unroll
              for (int r = 0; r < 4; ++r)
                if (sloc + r > qloc) e[r] = 0.f;
            }
            uint2 packed = {cvt_pk(e[0], e[1]), cvt_pk(e[2], e[3])};
            pa[rt][st] = __builtin_bit_cast(bf16x4, packed);
          }
        }
        // O += P V ; l += P . ones
#pragma unroll
        for (int st = 0; st < 4; ++st) {
#pragma unroll
          for (int dt = 0; dt < 4; ++dt) {
            const bf16x4 vb =
                *(const bf16x4*)(&Vs[(dt * 16 + ln) * 72 + st * 16 + 4 * g]);
#pragma unroll
            for (int rt = 0; rt < 2; ++rt)
              oacc[rt][dt] = mfma16(pa[rt][st], vb, oacc[rt][dt]);
          }
#pragma unroll
          for (int rt = 0; rt < 2; ++rt)
            lacc[rt] = mfma16(pa[rt][st], ones, lacc[rt]);
        }
      }
    }
    // epilogue for this phase
#pragma unroll
    for (int rt = 0; rt < 2; ++rt) {
      float linv[4];
#pragma unroll
      for (int r = 0; r < 4; ++r) linv[r] = 1.f / lacc[rt][r];
#pragma unroll
      for (int dt = 0; dt < 4; ++dt) {
        const unsigned p01 =
            cvt_pk(oacc[rt][dt][0] * linv[0], oacc[rt][dt][1] * linv[1]);
        const unsigned p23 =
            cvt_pk(oacc[rt][dt][2] * linv[2], oacc[rt][dt][3] * linv[3]);
        const u16 vv[4] = {(u16)p01, (u16)(p01 >> 16), (u16)p23, (u16)(p23 >> 16)};
#pragma unroll
        for (int r = 0; r < 4; ++r) {
          const int qg = q0 + wv * 32 + rt * 16 + 4 * g + r;
          AO[(size_t)(b * 2048 + qg) * 1024 + h * 64 + dt * 16 + ln] = vv[r];
        }
      }
    }
  }
}

// ---------- launch ----------
// Inputs FP32, output FP32; internal bf16. ws (72 MB):
//   [0,16M): xbf (phase 1) then AO (phase 2)
//   [16,22M): wt    [22,24M): wpbf
//   Q [24,40M)   K [40,56M)   VT [56,72M)
extern "C" void kernel_launch(void* const* d_in, const int* in_sizes, int n_in,
                              void* d_out, int out_size, void* d_ws, size_t ws_size,
                              hipStream_t stream) {
  const float* x  = (const float*)d_in[0];
  const float* Wq = (const float*)d_in[1];
  const float* Wk = (const float*)d_in[2];
  const float* Wv = (const float*)d_in[3];
  const float* Wp = (const float*)d_in[4];
  const float* bp = (const float*)d_in[5];
  float* out = (float*)d_out;

  char* ws = (char*)d_ws;
  const size_t MB = 1048576;
  u16* xbf  = (u16*)(ws);
  u16* aows = (u16*)(ws);
  u16* wt   = (u16*)(ws + 16 * MB);
  u16* wpbf = (u16*)(ws + 22 * MB);
  u16* qws  = (u16*)(ws + 24 * MB);
  u16* kws  = (u16*)(ws + 40 * MB);
  u16* vtws = (u16*)(ws + 56 * MB);

  // fused prep: x->bf16, Wq/Wk/Wv -> WT[3072][1024] bf16, Wp->bf16
  prep<<<dim3(5376), 256, 0, stream>>>(x, xbf, Wq, Wk, Wv, wt, Wp, wpbf);
  // QKV projection -> Q(prescaled),K [B,H,T,D]; V direct-transposed [B,H,D,T]
  gemm_bt<0><<<dim3(64, 24), 256, 0, stream>>>(xbf, wt, qws, kws, vtws,
                                               nullptr, nullptr);
  // causal flash attention -> AO [B,T,H*D] (overlays dead xbf)
  attn_kernel<<<dim3(64, 8), 256, 0, stream>>>(qws, kws, vtws, aows);
  // output projection: AO @ Wp^T + bp -> out FP32
  gemm_bt<1><<<dim3(64, 8), 256, 0, stream>>>(aows, wpbf, nullptr, nullptr,
                                              nullptr, out, bp);
}